// Round 11
// baseline (498.807 us; speedup 1.0000x reference)
//
#include <hip/hip_runtime.h>
#include <stdint.h>

#define B_ 8
#define N_ 2048
#define D_ 1024
#define E_ 8
#define F_ 4096
#define H_ 1024
#define T_ (B_*N_)

typedef unsigned short u16;
typedef unsigned int u32;
typedef __attribute__((ext_vector_type(8))) short short8;
typedef __attribute__((ext_vector_type(4))) float f32x4;

#define AS1 __attribute__((address_space(1)))
#define AS3 __attribute__((address_space(3)))

__device__ __forceinline__ void gll16(const void* g, void* l) {
  __builtin_amdgcn_global_load_lds((AS1 const void*)g, (AS3 void*)l, 16, 0, 0);
}

__device__ __forceinline__ u16 f2bf(float f) {
  u32 u = __float_as_uint(f);
  u32 r = (u + 0x7fffu + ((u >> 16) & 1u)) >> 16;
  return (u16)r;
}

// ---------- convert x fp32 -> bf16 ----------
__global__ void cvt_x(const float* __restrict__ x, u16* __restrict__ xb) {
  int i = blockIdx.x * blockDim.x + threadIdx.x;
  const int total = T_ * D_ / 8;
  for (; i < total; i += gridDim.x * blockDim.x) {
    float4 v0 = ((const float4*)x)[2*i];
    float4 v1 = ((const float4*)x)[2*i+1];
    uint4 o;
    o.x = (u32)f2bf(v0.x) | ((u32)f2bf(v0.y) << 16);
    o.y = (u32)f2bf(v0.z) | ((u32)f2bf(v0.w) << 16);
    o.z = (u32)f2bf(v1.x) | ((u32)f2bf(v1.y) << 16);
    o.w = (u32)f2bf(v1.z) | ((u32)f2bf(v1.w) << 16);
    ((uint4*)xb)[i] = o;
  }
}

// ---------- convert + transpose W1[e][d][f] -> w1t[e][f][d] bf16 ----------
__global__ void cvt_w1(const float* __restrict__ W1, u16* __restrict__ w1t) {
  __shared__ float tile[64][65];
  int e = blockIdx.z;
  int d0 = blockIdx.y * 64, f0 = blockIdx.x * 64;
  int tid = threadIdx.x;
  int r = tid >> 2, cs = (tid & 3) * 16;
  const float* src = W1 + ((size_t)e * D_ + d0) * F_ + f0;
  #pragma unroll
  for (int j = 0; j < 4; ++j) {
    float4 v = *(const float4*)&src[(size_t)r * F_ + cs + j*4];
    tile[r][cs + j*4 + 0] = v.x;
    tile[r][cs + j*4 + 1] = v.y;
    tile[r][cs + j*4 + 2] = v.z;
    tile[r][cs + j*4 + 3] = v.w;
  }
  __syncthreads();
  u32 vals[8];
  #pragma unroll
  for (int j = 0; j < 8; ++j) {
    u32 lo = f2bf(tile[cs + 2*j][r]);
    u32 hi = f2bf(tile[cs + 2*j + 1][r]);
    vals[j] = lo | (hi << 16);
  }
  uint4 A = {vals[0], vals[1], vals[2], vals[3]};
  uint4 Bv = {vals[4], vals[5], vals[6], vals[7]};
  uint4* dst = (uint4*)(w1t + ((size_t)e * F_ + f0 + r) * D_ + d0 + cs);
  dst[0] = A;
  dst[1] = Bv;
}

// ---------- router: fp32 logits, top-2, softmax -> dense gates [T][E] ----------
__global__ void router(const float* __restrict__ x, const float* __restrict__ Wg,
                       const float* __restrict__ bg, float* __restrict__ gdense) {
  int wave = (blockIdx.x * blockDim.x + threadIdx.x) >> 6;
  int lane = threadIdx.x & 63;
  if (wave >= T_) return;
  const float* xr = x + (size_t)wave * D_;
  float acc[8] = {0,0,0,0,0,0,0,0};
  for (int i = 0; i < D_/64; ++i) {
    int d = i*64 + lane;
    float xv = xr[d];
    const float4* wr = (const float4*)(Wg + (size_t)d * E_);
    float4 wa = wr[0], wb2 = wr[1];
    acc[0] += xv * wa.x;  acc[1] += xv * wa.y;
    acc[2] += xv * wa.z;  acc[3] += xv * wa.w;
    acc[4] += xv * wb2.x; acc[5] += xv * wb2.y;
    acc[6] += xv * wb2.z; acc[7] += xv * wb2.w;
  }
  #pragma unroll
  for (int e = 0; e < 8; ++e) {
    #pragma unroll
    for (int s = 32; s > 0; s >>= 1) acc[e] += __shfl_xor(acc[e], s);
  }
  if (lane == 0) {
    float v[8];
    #pragma unroll
    for (int e = 0; e < 8; ++e) v[e] = acc[e] + bg[e];
    int i1 = -1, i2 = -1;
    float b1v = -1e30f, b2v = -1e30f;
    #pragma unroll
    for (int e = 0; e < 8; ++e) {
      float vv = v[e];
      if (vv > b1v) { b2v = b1v; i2 = i1; b1v = vv; i1 = e; }
      else if (vv > b2v) { b2v = vv; i2 = e; }
    }
    float e2 = __expf(b2v - b1v);
    float inv = 1.f / (1.f + e2);
    float* gr = gdense + (size_t)wave * E_;
    #pragma unroll
    for (int e = 0; e < 8; ++e) gr[e] = 0.f;
    gr[i1] = inv;
    gr[i2] = e2 * inv;
  }
}

// ---------- compaction: per (b,e) ordered token list, padded to FULL N_ ----------
__global__ void compact(const float* __restrict__ gdense, int* __restrict__ lists,
                        float* __restrict__ glist, int* __restrict__ cntp,
                        float* __restrict__ G) {
  int be = blockIdx.x;
  int b = be >> 3, e = be & 7;
  __shared__ int warp_off[4];
  __shared__ float wsum[4];
  int tid = threadIdx.x;
  int lane = tid & 63, w = tid >> 6;
  int base = 0;
  float gsum = 0.f;
  for (int c = 0; c < N_; c += 256) {
    int t = b * N_ + c + tid;
    float g = gdense[(size_t)t * E_ + e];
    gsum += g;
    bool sel = g > 0.f;
    unsigned long long m = __ballot(sel);
    int my = __popcll(m & ((1ull << lane) - 1ull));
    int wcnt = __popcll(m);
    if (lane == 0) warp_off[w] = wcnt;
    __syncthreads();
    int off = 0;
    for (int i = 0; i < w; ++i) off += warp_off[i];
    int tot = warp_off[0] + warp_off[1] + warp_off[2] + warp_off[3];
    if (sel) {
      int pos = base + off + my;
      lists[be * N_ + pos] = t;
      glist[be * N_ + pos] = g;
    }
    base += tot;
    __syncthreads();
  }
  // pad with dummy token (gate 0) to FULL N_ so gemm1 can over-read safely
  for (int p = base + tid; p < N_; p += 256) {
    lists[be * N_ + p] = b * N_;
    glist[be * N_ + p] = 0.f;
  }
  if (tid == 0) cntp[be] = base;
  #pragma unroll
  for (int s = 32; s > 0; s >>= 1) gsum += __shfl_xor(gsum, s);
  if (lane == 0) wsum[w] = gsum;
  __syncthreads();
  if (tid == 0) G[be] = wsum[0] + wsum[1] + wsum[2] + wsum[3];
}

// ---------- out init with bias-2 term: out[b][h] = sum_e G[b,e]*b2[e][h] ----------
__global__ void init_out(const float* __restrict__ G, const float* __restrict__ b2,
                         float* __restrict__ out) {
  int i = blockIdx.x * 256 + threadIdx.x;
  int b = i >> 10, h = i & 1023;
  float acc = 0.f;
  #pragma unroll
  for (int e = 0; e < 8; ++e) acc += G[b * E_ + e] * b2[e * H_ + h];
  out[i] = acc;
}

// ---------- GEMM1: 256x256, counted vmcnt(4), A dbuf + B tbuf (160KB LDS) ----------
// Staging/read swizzle identical to R10. Per tile: vmcnt(4) [newest 4 = B(t+1)
// stay in flight across the barrier] -> barrier -> STAGE_A(t+1), STAGE_B(t+2)
// -> pipelined ds_reads + 4 setprio MFMA clusters. B gets ~2 tiles of latency
// cover, A ~1 tile; the pipe never drains mid-loop.
__launch_bounds__(512, 1)
__global__ void gemm1(const u16* __restrict__ xb, const u16* __restrict__ w1t,
                      const float* __restrict__ b1, const int* __restrict__ lists,
                      const float* __restrict__ glist, const int* __restrict__ cntp,
                      float* __restrict__ sbuf) {
  int bid = blockIdx.x;
  int e     = bid & 7;          // XCD id == expert
  int idx   = bid >> 3;
  int ft    = idx & 15;         // 256-wide f tile
  int b     = (idx >> 4) & 7;
  int chunk = idx >> 7;         // 256-row chunk
  int be = b * 8 + e;
  int cnt = cntp[be];
  if (chunk * 256 >= cnt) return;
  int fbase = ft * 256;

  __shared__ u16 sA[2][16384];   // [buf][row256][slot8][8elem], swizzle-stored
  __shared__ u16 sB[3][16384];   // triple-buffered B

  int tid  = threadIdx.x;
  int lane = tid & 63;
  int w    = tid >> 6;
  int wm   = w >> 2;             // rows wm*128
  int wn   = w & 3;              // f cols wn*64
  int fr   = lane & 15;
  int kq   = lane >> 4;          // 0..3
  int r8   = lane >> 3;          // 0..7 staging row-sub
  int sx   = lane & 7;           // staging slot
  int srcSlot = ((sx ^ r8) << 4);  // swizzled byte offset within 128B row segment

  // per-lane staging sources; LDS row = j*64 + w*8 + r8 (linear fill order)
  const int* lrow = lists + be * N_ + chunk * 256;
  const char* aP[4];
  const char* bP[4];
  #pragma unroll
  for (int j = 0; j < 4; ++j) {
    int row = j * 64 + w * 8 + r8;
    int tok = lrow[row];
    aP[j] = (const char*)xb + (size_t)tok * 2048 + srcSlot;
    bP[j] = (const char*)w1t + (size_t)(e * F_ + fbase + row) * 2048 + srcSlot;
  }
  int dOff = w * 512;            // u16 units; wave-uniform; +j*4096; HW adds lane*16B

  // read-side indices (short8 units): elem = row*8 + (ks ^ (row&7)); row&7==sx
  int ksl0 = kq ^ sx;            // kh=0
  int ksl1 = (4 + kq) ^ sx;      // kh=1
  int arow = (wm * 128 + fr) * 8;   // + mh*512 + i*128
  int brow = (wn * 64 + fr) * 8;    // + j*128

#define SCHED __builtin_amdgcn_sched_barrier(0)
#define STAGE_A(t_) do { \
    _Pragma("unroll") for (int j_ = 0; j_ < 4; ++j_) \
      gll16(aP[j_] + (t_) * 128, &sA[(t_) & 1][j_ * 4096 + dOff]); \
  } while (0)
#define STAGE_B(t_) do { \
    _Pragma("unroll") for (int j_ = 0; j_ < 4; ++j_) \
      gll16(bP[j_] + (t_) * 128, &sB[(t_) % 3][j_ * 4096 + dOff]); \
  } while (0)
#define RDA(V_, ks_, mh_) do { _Pragma("unroll") for (int i_ = 0; i_ < 4; ++i_) \
    V_[i_] = Ab[arow + (mh_) * 512 + i_ * 128 + (ks_)]; } while (0)
#define RDB(V_, ks_) do { _Pragma("unroll") for (int j_ = 0; j_ < 4; ++j_) \
    V_[j_] = Bb[brow + j_ * 128 + (ks_)]; } while (0)
#define DOMFMA(mh_, A_, B_) do { _Pragma("unroll") for (int i_ = 0; i_ < 4; ++i_) \
    _Pragma("unroll") for (int j_ = 0; j_ < 4; ++j_) \
      acc[(mh_)*4 + i_][j_] = __builtin_amdgcn_mfma_f32_16x16x32_bf16(A_[i_], B_[j_], acc[(mh_)*4 + i_][j_], 0, 0, 0); \
  } while (0)

  f32x4 acc[8][4];
  #pragma unroll
  for (int i = 0; i < 8; ++i)
    #pragma unroll
    for (int j = 0; j < 4; ++j) acc[i][j] = (f32x4){0.f, 0.f, 0.f, 0.f};

  // prologue: A(0), B(0), B(1) in flight (issue order matters for vmcnt counts)
  STAGE_A(0);
  STAGE_B(0);
  STAGE_B(1);

  const int NK = D_ / 64;   // 16
  for (int t = 0; t < NK; ++t) {
    const short8* Ab = (const short8*)&sA[t & 1][0];
    const short8* Bb = (const short8*)&sB[t % 3][0];

    // newest 4 outstanding = B(t+1); everything older (A(t), B(t)) must land.
    if (t + 1 < NK) asm volatile("s_waitcnt vmcnt(4)" ::: "memory");
    else            asm volatile("s_waitcnt vmcnt(0)" ::: "memory");
    __builtin_amdgcn_s_barrier();
    SCHED;

    if (t + 1 < NK) STAGE_A(t + 1);
    if (t + 2 < NK) STAGE_B(t + 2);

    short8 a0[4], a1[4], a2[4], a3[4], b0[4], b2[4];
    RDA(a0, ksl0, 0); RDB(b0, ksl0);
    RDA(a1, ksl0, 1);
    SCHED;
    __builtin_amdgcn_s_setprio(1); DOMFMA(0, a0, b0); __builtin_amdgcn_s_setprio(0);
    RDA(a2, ksl1, 0); RDB(b2, ksl1);
    SCHED;
    __builtin_amdgcn_s_setprio(1); DOMFMA(1, a1, b0); __builtin_amdgcn_s_setprio(0);
    RDA(a3, ksl1, 1);
    SCHED;
    __builtin_amdgcn_s_setprio(1); DOMFMA(0, a2, b2); __builtin_amdgcn_s_setprio(0);
    SCHED;
    __builtin_amdgcn_s_setprio(1); DOMFMA(1, a3, b2); __builtin_amdgcn_s_setprio(0);
    SCHED;
  }
#undef STAGE_A
#undef STAGE_B
#undef RDA
#undef RDB
#undef DOMFMA

  // epilogue: relu(acc + b1) * gate, column-sum over the chunk's 256 rows
  float b1f[4];
  #pragma unroll
  for (int j = 0; j < 4; ++j)
    b1f[j] = b1[e * F_ + fbase + wn * 64 + j * 16 + fr];
  const float* gRow = glist + be * N_ + chunk * 256;
  float osum[4] = {0.f, 0.f, 0.f, 0.f};
  #pragma unroll
  for (int i = 0; i < 8; ++i) {
    float4 g = *(const float4*)&gRow[wm * 128 + i * 16 + kq * 4];
    #pragma unroll
    for (int j = 0; j < 4; ++j) {
      osum[j] += fmaxf(acc[i][j][0] + b1f[j], 0.f) * g.x
               + fmaxf(acc[i][j][1] + b1f[j], 0.f) * g.y
               + fmaxf(acc[i][j][2] + b1f[j], 0.f) * g.z
               + fmaxf(acc[i][j][3] + b1f[j], 0.f) * g.w;
    }
  }
  #pragma unroll
  for (int j = 0; j < 4; ++j) {
    osum[j] += __shfl_xor(osum[j], 16);
    osum[j] += __shfl_xor(osum[j], 32);
  }
  float* sRed = (float*)&sA[0][0];
  __syncthreads();
  if (wm == 0 && lane < 16) {
    #pragma unroll
    for (int j = 0; j < 4; ++j)
      sRed[wn * 64 + j * 16 + lane] = osum[j];
  }
  __syncthreads();
  if (wm == 1 && lane < 16) {
    #pragma unroll
    for (int j = 0; j < 4; ++j) {
      int fc = wn * 64 + j * 16 + lane;
      atomicAdd(&sbuf[(size_t)be * F_ + fbase + fc], sRed[fc] + osum[j]);
    }
  }
}

// ---------- GEMM2: out[b][h] += sum_f s[b,e,f] * W2[e][f][h] (memory-bound) ----------
__global__ void gemm2(const float* __restrict__ sbuf, const float* __restrict__ W2,
                      float* __restrict__ out) {
  int fc = blockIdx.x;   // 16 chunks of 256 f
  int ht = blockIdx.y;   // 4 tiles of 256 h
  int e  = blockIdx.z;   // 8 experts
  __shared__ float sS[8][256];
  int tid = threadIdx.x;
  #pragma unroll
  for (int b = 0; b < 8; ++b)
    sS[b][tid] = sbuf[((size_t)(b * E_ + e)) * F_ + fc * 256 + tid];
  __syncthreads();
  int h = ht * 256 + tid;
  float acc[8] = {0,0,0,0,0,0,0,0};
  const float* w2p = W2 + (size_t)e * F_ * H_ + (size_t)(fc * 256) * H_ + h;
  for (int f = 0; f < 256; ++f) {
    float wv = w2p[(size_t)f * H_];
    #pragma unroll
    for (int b = 0; b < 8; ++b) acc[b] += sS[b][f] * wv;
  }
  #pragma unroll
  for (int b = 0; b < 8; ++b) atomicAdd(&out[b * H_ + h], acc[b]);
}

extern "C" void kernel_launch(void* const* d_in, const int* in_sizes, int n_in,
                              void* d_out, int out_size, void* d_ws, size_t ws_size,
                              hipStream_t stream) {
  const float* x  = (const float*)d_in[0];
  const float* Wg = (const float*)d_in[1];
  const float* bg = (const float*)d_in[2];
  const float* W1 = (const float*)d_in[3];
  const float* b1 = (const float*)d_in[4];
  const float* W2 = (const float*)d_in[5];
  const float* b2 = (const float*)d_in[6];
  float* out = (float*)d_out;

  char* ws = (char*)d_ws;
  u16*   xb     = (u16*)(ws);
  u16*   w1t    = (u16*)(ws + 33554432);
  float* gdense = (float*)(ws + 100663296);
  int*   lists  = (int*)(ws + 101187584);
  float* glist  = (float*)(ws + 101711872);
  int*   cntp   = (int*)(ws + 102236160);
  float* G      = (float*)(ws + 102236416);
  float* sbuf   = (float*)(ws + 102236672);

  hipMemsetAsync(sbuf, 0, (size_t)64 * F_ * sizeof(float), stream);
  cvt_x<<<8192, 256, 0, stream>>>(x, xb);
  cvt_w1<<<dim3(F_/64, D_/64, E_), 256, 0, stream>>>(W1, w1t);
  router<<<T_/4, 256, 0, stream>>>(x, Wg, bg, gdense);
  compact<<<64, 256, 0, stream>>>(gdense, lists, glist, cntp, G);
  init_out<<<(B_*H_)/256, 256, 0, stream>>>(G, b2, out);
  gemm1<<<8192, 512, 0, stream>>>(xb, w1t, b1, lists, glist, cntp, sbuf);
  gemm2<<<dim3(16, 4, 8), 256, 0, stream>>>(sbuf, W2, out);
}

// Round 12
// 398.465 us; speedup vs baseline: 1.2518x; 1.2518x over previous
//
#include <hip/hip_runtime.h>
#include <stdint.h>

#define B_ 8
#define N_ 2048
#define D_ 1024
#define E_ 8
#define F_ 4096
#define H_ 1024
#define T_ (B_*N_)
#define LS_ 8192   // per-expert concat list stride

typedef unsigned short u16;
typedef unsigned int u32;
typedef __attribute__((ext_vector_type(8))) short short8;
typedef __attribute__((ext_vector_type(4))) float f32x4;

#define AS1 __attribute__((address_space(1)))
#define AS3 __attribute__((address_space(3)))

__device__ __forceinline__ void gll16(const void* g, void* l) {
  __builtin_amdgcn_global_load_lds((AS1 const void*)g, (AS3 void*)l, 16, 0, 0);
}

__device__ __forceinline__ u16 f2bf(float f) {
  u32 u = __float_as_uint(f);
  u32 r = (u + 0x7fffu + ((u >> 16) & 1u)) >> 16;
  return (u16)r;
}

// ---------- convert x fp32 -> bf16 ----------
__global__ void cvt_x(const float* __restrict__ x, u16* __restrict__ xb) {
  int i = blockIdx.x * blockDim.x + threadIdx.x;
  const int total = T_ * D_ / 8;
  for (; i < total; i += gridDim.x * blockDim.x) {
    float4 v0 = ((const float4*)x)[2*i];
    float4 v1 = ((const float4*)x)[2*i+1];
    uint4 o;
    o.x = (u32)f2bf(v0.x) | ((u32)f2bf(v0.y) << 16);
    o.y = (u32)f2bf(v0.z) | ((u32)f2bf(v0.w) << 16);
    o.z = (u32)f2bf(v1.x) | ((u32)f2bf(v1.y) << 16);
    o.w = (u32)f2bf(v1.z) | ((u32)f2bf(v1.w) << 16);
    ((uint4*)xb)[i] = o;
  }
}

// ---------- convert + transpose W1[e][d][f] -> w1t[e][f][d] bf16 ----------
__global__ void cvt_w1(const float* __restrict__ W1, u16* __restrict__ w1t) {
  __shared__ float tile[64][65];
  int e = blockIdx.z;
  int d0 = blockIdx.y * 64, f0 = blockIdx.x * 64;
  int tid = threadIdx.x;
  int r = tid >> 2, cs = (tid & 3) * 16;
  const float* src = W1 + ((size_t)e * D_ + d0) * F_ + f0;
  #pragma unroll
  for (int j = 0; j < 4; ++j) {
    float4 v = *(const float4*)&src[(size_t)r * F_ + cs + j*4];
    tile[r][cs + j*4 + 0] = v.x;
    tile[r][cs + j*4 + 1] = v.y;
    tile[r][cs + j*4 + 2] = v.z;
    tile[r][cs + j*4 + 3] = v.w;
  }
  __syncthreads();
  u32 vals[8];
  #pragma unroll
  for (int j = 0; j < 8; ++j) {
    u32 lo = f2bf(tile[cs + 2*j][r]);
    u32 hi = f2bf(tile[cs + 2*j + 1][r]);
    vals[j] = lo | (hi << 16);
  }
  uint4 A = {vals[0], vals[1], vals[2], vals[3]};
  uint4 Bv = {vals[4], vals[5], vals[6], vals[7]};
  uint4* dst = (uint4*)(w1t + ((size_t)e * F_ + f0 + r) * D_ + d0 + cs);
  dst[0] = A;
  dst[1] = Bv;
}

// ---------- router: fp32 logits, top-2, softmax -> dense gates [T][E] ----------
__global__ void router(const float* __restrict__ x, const float* __restrict__ Wg,
                       const float* __restrict__ bg, float* __restrict__ gdense) {
  int wave = (blockIdx.x * blockDim.x + threadIdx.x) >> 6;
  int lane = threadIdx.x & 63;
  if (wave >= T_) return;
  const float* xr = x + (size_t)wave * D_;
  float acc[8] = {0,0,0,0,0,0,0,0};
  for (int i = 0; i < D_/64; ++i) {
    int d = i*64 + lane;
    float xv = xr[d];
    const float4* wr = (const float4*)(Wg + (size_t)d * E_);
    float4 wa = wr[0], wb2 = wr[1];
    acc[0] += xv * wa.x;  acc[1] += xv * wa.y;
    acc[2] += xv * wa.z;  acc[3] += xv * wa.w;
    acc[4] += xv * wb2.x; acc[5] += xv * wb2.y;
    acc[6] += xv * wb2.z; acc[7] += xv * wb2.w;
  }
  #pragma unroll
  for (int e = 0; e < 8; ++e) {
    #pragma unroll
    for (int s = 32; s > 0; s >>= 1) acc[e] += __shfl_xor(acc[e], s);
  }
  if (lane == 0) {
    float v[8];
    #pragma unroll
    for (int e = 0; e < 8; ++e) v[e] = acc[e] + bg[e];
    int i1 = -1, i2 = -1;
    float b1v = -1e30f, b2v = -1e30f;
    #pragma unroll
    for (int e = 0; e < 8; ++e) {
      float vv = v[e];
      if (vv > b1v) { b2v = b1v; i2 = i1; b1v = vv; i1 = e; }
      else if (vv > b2v) { b2v = vv; i2 = e; }
    }
    float e2 = __expf(b2v - b1v);
    float inv = 1.f / (1.f + e2);
    float* gr = gdense + (size_t)wave * E_;
    #pragma unroll
    for (int e = 0; e < 8; ++e) gr[e] = 0.f;
    gr[i1] = inv;
    gr[i2] = e2 * inv;
  }
}

// ---------- compaction: per (b,e) ordered token list ----------
__global__ void compact(const float* __restrict__ gdense, int* __restrict__ lists,
                        float* __restrict__ glist, int* __restrict__ cntp,
                        float* __restrict__ G) {
  int be = blockIdx.x;
  int b = be >> 3, e = be & 7;
  __shared__ int warp_off[4];
  __shared__ float wsum[4];
  int tid = threadIdx.x;
  int lane = tid & 63, w = tid >> 6;
  int base = 0;
  float gsum = 0.f;
  for (int c = 0; c < N_; c += 256) {
    int t = b * N_ + c + tid;
    float g = gdense[(size_t)t * E_ + e];
    gsum += g;
    bool sel = g > 0.f;
    unsigned long long m = __ballot(sel);
    int my = __popcll(m & ((1ull << lane) - 1ull));
    int wcnt = __popcll(m);
    if (lane == 0) warp_off[w] = wcnt;
    __syncthreads();
    int off = 0;
    for (int i = 0; i < w; ++i) off += warp_off[i];
    int tot = warp_off[0] + warp_off[1] + warp_off[2] + warp_off[3];
    if (sel) {
      int pos = base + off + my;
      lists[be * N_ + pos] = t;
      glist[be * N_ + pos] = g;
    }
    base += tot;
    __syncthreads();
  }
  if (tid == 0) cntp[be] = base;
  #pragma unroll
  for (int s = 32; s > 0; s >>= 1) gsum += __shfl_xor(gsum, s);
  if (lane == 0) wsum[w] = gsum;
  __syncthreads();
  if (tid == 0) G[be] = wsum[0] + wsum[1] + wsum[2] + wsum[3];
}

// ---------- concat per-expert lists across b; pad to 256-multiple ----------
__global__ void concatE(const int* __restrict__ lists, const float* __restrict__ glist,
                        const int* __restrict__ cntp, int* __restrict__ lists2,
                        float* __restrict__ glist2, int* __restrict__ lenp) {
  int e = blockIdx.x, tid = threadIdx.x;
  __shared__ int off[9];
  if (tid == 0) {
    int s = 0;
    for (int b = 0; b < 8; ++b) { off[b] = s; s += cntp[b * 8 + e]; }
    off[8] = s;
    lenp[e] = (s + 255) & ~255;
  }
  __syncthreads();
  for (int b = 0; b < 8; ++b) {
    int base = off[b], c = cntp[b * 8 + e];
    for (int i = tid; i < c; i += 256) {
      lists2[e * LS_ + base + i] = lists[(b * 8 + e) * N_ + i];
      glist2[e * LS_ + base + i] = glist[(b * 8 + e) * N_ + i];
    }
  }
  __syncthreads();
  int s = off[8], p = (s + 255) & ~255;
  for (int i = s + tid; i < p; i += 256) {
    lists2[e * LS_ + i] = 0;     // token 0 (b=0), gate 0
    glist2[e * LS_ + i] = 0.f;
  }
}

// ---------- out init with bias-2 term: out[b][h] = sum_e G[b,e]*b2[e][h] ----------
__global__ void init_out(const float* __restrict__ G, const float* __restrict__ b2,
                         float* __restrict__ out) {
  int i = blockIdx.x * 256 + threadIdx.x;
  int b = i >> 10, h = i & 1023;
  float acc = 0.f;
  #pragma unroll
  for (int e = 0; e < 8; ++e) acc += G[b * E_ + e] * b2[e * H_ + h];
  out[i] = acc;
}

// ---------- GEMM1: R10 schedule verbatim; per-expert concat lists ----------
// Block = (e, ft256, chunk256-of-concat-list). Chunk spans <=1 batch boundary;
// epilogue splits gated column-sum into two bins (bLo / bLo+1) via tok>>11.
__launch_bounds__(512, 1)
__global__ void gemm1(const u16* __restrict__ xb, const u16* __restrict__ w1t,
                      const float* __restrict__ b1, const int* __restrict__ lists2,
                      const float* __restrict__ glist2, const int* __restrict__ lenp,
                      float* __restrict__ sbuf) {
  int bid = blockIdx.x;
  int e     = bid & 7;          // XCD id == expert
  int idx   = bid >> 3;
  int ft    = idx & 15;         // 256-wide f tile
  int chunk = idx >> 4;         // 0..17 chunk of concat list
  if (chunk * 256 >= lenp[e]) return;
  int fbase = ft * 256;

  __shared__ u16 sA[2][16384];   // [buf][row256][slot8][8elem], swizzle-stored
  __shared__ u16 sB[2][16384];

  int tid  = threadIdx.x;
  int lane = tid & 63;
  int w    = tid >> 6;
  int wm   = w >> 2;             // rows wm*128
  int wn   = w & 3;              // f cols wn*64
  int fr   = lane & 15;
  int kq   = lane >> 4;          // 0..3
  int r8   = lane >> 3;          // 0..7 staging row-sub
  int sx   = lane & 7;           // staging slot
  int srcSlot = ((sx ^ r8) << 4);  // swizzled byte offset within 128B row segment

  const int* lrow = lists2 + e * LS_ + chunk * 256;
  const char* aP[4];
  const char* bP[4];
  #pragma unroll
  for (int j = 0; j < 4; ++j) {
    int row = j * 64 + w * 8 + r8;
    int tok = lrow[row];
    aP[j] = (const char*)xb + (size_t)tok * 2048 + srcSlot;
    bP[j] = (const char*)w1t + (size_t)(e * F_ + fbase + row) * 2048 + srcSlot;
  }
  int dOff = w * 512;            // u16 units; wave-uniform; +j*4096; HW adds lane*16B

  // read-side indices (short8 units): elem = row*8 + (ks ^ (row&7)); row&7==sx
  int ksl0 = kq ^ sx;            // kh=0
  int ksl1 = (4 + kq) ^ sx;      // kh=1
  int arow = (wm * 128 + fr) * 8;   // + mh*512 + i*128
  int brow = (wn * 64 + fr) * 8;    // + j*128

#define SCHED __builtin_amdgcn_sched_barrier(0)
#define STAGE(t_, bf_) do { \
    _Pragma("unroll") for (int j_ = 0; j_ < 4; ++j_) \
      gll16(aP[j_] + (t_) * 128, &sA[bf_][j_ * 4096 + dOff]); \
    _Pragma("unroll") for (int j_ = 0; j_ < 4; ++j_) \
      gll16(bP[j_] + (t_) * 128, &sB[bf_][j_ * 4096 + dOff]); \
  } while (0)
#define RDA(V_, ks_, mh_) do { _Pragma("unroll") for (int i_ = 0; i_ < 4; ++i_) \
    V_[i_] = Ab[arow + (mh_) * 512 + i_ * 128 + (ks_)]; } while (0)
#define RDB(V_, ks_) do { _Pragma("unroll") for (int j_ = 0; j_ < 4; ++j_) \
    V_[j_] = Bb[brow + j_ * 128 + (ks_)]; } while (0)
#define DOMFMA(mh_, A_, B_) do { _Pragma("unroll") for (int i_ = 0; i_ < 4; ++i_) \
    _Pragma("unroll") for (int j_ = 0; j_ < 4; ++j_) \
      acc[(mh_)*4 + i_][j_] = __builtin_amdgcn_mfma_f32_16x16x32_bf16(A_[i_], B_[j_], acc[(mh_)*4 + i_][j_], 0, 0, 0); \
  } while (0)

  f32x4 acc[8][4];
  #pragma unroll
  for (int i = 0; i < 8; ++i)
    #pragma unroll
    for (int j = 0; j < 4; ++j) acc[i][j] = (f32x4){0.f, 0.f, 0.f, 0.f};

  // prologue: tile 0 in flight
  STAGE(0, 0);

  const int NK = D_ / 64;   // 16
  for (int t = 0; t < NK; ++t) {
    int bf = t & 1;
    const short8* Ab = (const short8*)&sA[bf][0];
    const short8* Bb = (const short8*)&sB[bf][0];

    asm volatile("s_waitcnt vmcnt(0)" ::: "memory");   // own tile-t loads landed
    __builtin_amdgcn_s_barrier();                      // all waves' loads landed
    SCHED;

    short8 a0[4], a1[4], a2[4], a3[4], b0[4], b2[4];
    RDA(a0, ksl0, 0); RDB(b0, ksl0);
    RDA(a1, ksl0, 1);
    if (t + 1 < NK) STAGE(t + 1, bf ^ 1);
    SCHED;
    __builtin_amdgcn_s_setprio(1); DOMFMA(0, a0, b0); __builtin_amdgcn_s_setprio(0);
    RDA(a2, ksl1, 0); RDB(b2, ksl1);
    SCHED;
    __builtin_amdgcn_s_setprio(1); DOMFMA(1, a1, b0); __builtin_amdgcn_s_setprio(0);
    RDA(a3, ksl1, 1);
    SCHED;
    __builtin_amdgcn_s_setprio(1); DOMFMA(0, a2, b2); __builtin_amdgcn_s_setprio(0);
    SCHED;
    __builtin_amdgcn_s_setprio(1); DOMFMA(1, a3, b2); __builtin_amdgcn_s_setprio(0);
    SCHED;
  }
#undef STAGE
#undef RDA
#undef RDB
#undef DOMFMA

  // epilogue: relu(acc + b1) * gate, column-sum split by batch bin
  float b1f[4];
  #pragma unroll
  for (int j = 0; j < 4; ++j)
    b1f[j] = b1[e * F_ + fbase + wn * 64 + j * 16 + fr];
  const float* gRow = glist2 + e * LS_ + chunk * 256;
  int bLo = lrow[0] >> 11;
  float osL[4] = {0.f, 0.f, 0.f, 0.f};
  float osH[4] = {0.f, 0.f, 0.f, 0.f};
  #pragma unroll
  for (int i = 0; i < 8; ++i) {
    int rr = wm * 128 + i * 16 + kq * 4;
    float4 g = *(const float4*)&gRow[rr];
    int4  tv = *(const int4*)&lrow[rr];
    float gl0 = ((tv.x >> 11) == bLo) ? g.x : 0.f;
    float gl1 = ((tv.y >> 11) == bLo) ? g.y : 0.f;
    float gl2 = ((tv.z >> 11) == bLo) ? g.z : 0.f;
    float gl3 = ((tv.w >> 11) == bLo) ? g.w : 0.f;
    float gh0 = g.x - gl0, gh1 = g.y - gl1, gh2 = g.z - gl2, gh3 = g.w - gl3;
    #pragma unroll
    for (int j = 0; j < 4; ++j) {
      float v0 = fmaxf(acc[i][j][0] + b1f[j], 0.f);
      float v1 = fmaxf(acc[i][j][1] + b1f[j], 0.f);
      float v2 = fmaxf(acc[i][j][2] + b1f[j], 0.f);
      float v3 = fmaxf(acc[i][j][3] + b1f[j], 0.f);
      osL[j] += v0 * gl0 + v1 * gl1 + v2 * gl2 + v3 * gl3;
      osH[j] += v0 * gh0 + v1 * gh1 + v2 * gh2 + v3 * gh3;
    }
  }
  #pragma unroll
  for (int j = 0; j < 4; ++j) {
    osL[j] += __shfl_xor(osL[j], 16);
    osL[j] += __shfl_xor(osL[j], 32);
    osH[j] += __shfl_xor(osH[j], 16);
    osH[j] += __shfl_xor(osH[j], 32);
  }
  float* sRedL = (float*)&sA[0][0];
  float* sRedH = sRedL + 256;
  __syncthreads();
  if (wm == 0 && lane < 16) {
    #pragma unroll
    for (int j = 0; j < 4; ++j) {
      sRedL[wn * 64 + j * 16 + lane] = osL[j];
      sRedH[wn * 64 + j * 16 + lane] = osH[j];
    }
  }
  __syncthreads();
  if (wm == 1 && lane < 16) {
    int beL = bLo * 8 + e;
    bool hasHi = bLo < 7;
    int beH = (bLo + 1) * 8 + e;
    #pragma unroll
    for (int j = 0; j < 4; ++j) {
      int fc = wn * 64 + j * 16 + lane;
      atomicAdd(&sbuf[(size_t)beL * F_ + fbase + fc], sRedL[fc] + osL[j]);
      if (hasHi)
        atomicAdd(&sbuf[(size_t)beH * F_ + fbase + fc], sRedH[fc] + osH[j]);
    }
  }
}

// ---------- GEMM2: out[b][h] += sum_f s[b,e,f] * W2[e][f][h] (memory-bound) ----------
__global__ void gemm2(const float* __restrict__ sbuf, const float* __restrict__ W2,
                      float* __restrict__ out) {
  int fc = blockIdx.x;   // 16 chunks of 256 f
  int ht = blockIdx.y;   // 4 tiles of 256 h
  int e  = blockIdx.z;   // 8 experts
  __shared__ float sS[8][256];
  int tid = threadIdx.x;
  #pragma unroll
  for (int b = 0; b < 8; ++b)
    sS[b][tid] = sbuf[((size_t)(b * E_ + e)) * F_ + fc * 256 + tid];
  __syncthreads();
  int h = ht * 256 + tid;
  float acc[8] = {0,0,0,0,0,0,0,0};
  const float* w2p = W2 + (size_t)e * F_ * H_ + (size_t)(fc * 256) * H_ + h;
  for (int f = 0; f < 256; ++f) {
    float wv = w2p[(size_t)f * H_];
    #pragma unroll
    for (int b = 0; b < 8; ++b) acc[b] += sS[b][f] * wv;
  }
  #pragma unroll
  for (int b = 0; b < 8; ++b) atomicAdd(&out[b * H_ + h], acc[b]);
}

extern "C" void kernel_launch(void* const* d_in, const int* in_sizes, int n_in,
                              void* d_out, int out_size, void* d_ws, size_t ws_size,
                              hipStream_t stream) {
  const float* x  = (const float*)d_in[0];
  const float* Wg = (const float*)d_in[1];
  const float* bg = (const float*)d_in[2];
  const float* W1 = (const float*)d_in[3];
  const float* b1 = (const float*)d_in[4];
  const float* W2 = (const float*)d_in[5];
  const float* b2 = (const float*)d_in[6];
  float* out = (float*)d_out;

  char* ws = (char*)d_ws;
  u16*   xb     = (u16*)(ws);
  u16*   w1t    = (u16*)(ws + 33554432);
  float* gdense = (float*)(ws + 100663296);
  int*   lists  = (int*)(ws + 101187584);
  float* glist  = (float*)(ws + 101711872);
  int*   cntp   = (int*)(ws + 102236160);
  float* G      = (float*)(ws + 102236416);
  float* sbuf   = (float*)(ws + 102236672);
  int*   lists2 = (int*)(ws + 103285248);
  float* glist2 = (float*)(ws + 103547392);
  int*   lenp   = (int*)(ws + 103809536);

  hipMemsetAsync(sbuf, 0, (size_t)64 * F_ * sizeof(float), stream);
  cvt_x<<<8192, 256, 0, stream>>>(x, xb);
  cvt_w1<<<dim3(F_/64, D_/64, E_), 256, 0, stream>>>(W1, w1t);
  router<<<T_/4, 256, 0, stream>>>(x, Wg, bg, gdense);
  compact<<<64, 256, 0, stream>>>(gdense, lists, glist, cntp, G);
  concatE<<<8, 256, 0, stream>>>(lists, glist, cntp, lists2, glist2, lenp);
  init_out<<<(B_*H_)/256, 256, 0, stream>>>(G, b2, out);
  gemm1<<<8*16*18, 512, 0, stream>>>(xb, w1t, b1, lists2, glist2, lenp, sbuf);
  gemm2<<<dim3(16, 4, 8), 256, 0, stream>>>(sbuf, W2, out);
}

// Round 13
// 385.331 us; speedup vs baseline: 1.2945x; 1.0341x over previous
//
#include <hip/hip_runtime.h>
#include <stdint.h>

#define B_ 8
#define N_ 2048
#define D_ 1024
#define E_ 8
#define F_ 4096
#define H_ 1024
#define T_ (B_*N_)
#define LS_ 8192   // per-expert concat list stride

typedef unsigned short u16;
typedef unsigned int u32;
typedef __attribute__((ext_vector_type(8))) short short8;
typedef __attribute__((ext_vector_type(4))) float f32x4;

#define AS1 __attribute__((address_space(1)))
#define AS3 __attribute__((address_space(3)))

__device__ __forceinline__ void gll16(const void* g, void* l) {
  __builtin_amdgcn_global_load_lds((AS1 const void*)g, (AS3 void*)l, 16, 0, 0);
}

__device__ __forceinline__ u16 f2bf(float f) {
  u32 u = __float_as_uint(f);
  u32 r = (u + 0x7fffu + ((u >> 16) & 1u)) >> 16;
  return (u16)r;
}

// ---------- convert + transpose W1[e][d][f] -> w1t[e][f][d] bf16 ----------
__global__ void cvt_w1(const float* __restrict__ W1, u16* __restrict__ w1t) {
  __shared__ float tile[64][65];
  int e = blockIdx.z;
  int d0 = blockIdx.y * 64, f0 = blockIdx.x * 64;
  int tid = threadIdx.x;
  int r = tid >> 2, cs = (tid & 3) * 16;
  const float* src = W1 + ((size_t)e * D_ + d0) * F_ + f0;
  #pragma unroll
  for (int j = 0; j < 4; ++j) {
    float4 v = *(const float4*)&src[(size_t)r * F_ + cs + j*4];
    tile[r][cs + j*4 + 0] = v.x;
    tile[r][cs + j*4 + 1] = v.y;
    tile[r][cs + j*4 + 2] = v.z;
    tile[r][cs + j*4 + 3] = v.w;
  }
  __syncthreads();
  u32 vals[8];
  #pragma unroll
  for (int j = 0; j < 8; ++j) {
    u32 lo = f2bf(tile[cs + 2*j][r]);
    u32 hi = f2bf(tile[cs + 2*j + 1][r]);
    vals[j] = lo | (hi << 16);
  }
  uint4 A = {vals[0], vals[1], vals[2], vals[3]};
  uint4 Bv = {vals[4], vals[5], vals[6], vals[7]};
  uint4* dst = (uint4*)(w1t + ((size_t)e * F_ + f0 + r) * D_ + d0 + cs);
  dst[0] = A;
  dst[1] = Bv;
}

// ---------- fused router + x->bf16 convert ----------
// One wave per token: stream x row once, emit bf16 copy + fp32 logits top-2.
__global__ void router(const float* __restrict__ x, const float* __restrict__ Wg,
                       const float* __restrict__ bg, float* __restrict__ gdense,
                       u16* __restrict__ xb) {
  int wave = (blockIdx.x * blockDim.x + threadIdx.x) >> 6;
  int lane = threadIdx.x & 63;
  if (wave >= T_) return;
  const float* xr = x + (size_t)wave * D_;
  u16* xbr = xb + (size_t)wave * D_;
  float acc[8] = {0,0,0,0,0,0,0,0};
  for (int i = 0; i < D_/64; ++i) {
    int d = i*64 + lane;
    float xv = xr[d];
    xbr[d] = f2bf(xv);                      // fused bf16 convert (was cvt_x)
    const float4* wr = (const float4*)(Wg + (size_t)d * E_);
    float4 wa = wr[0], wb2 = wr[1];
    acc[0] += xv * wa.x;  acc[1] += xv * wa.y;
    acc[2] += xv * wa.z;  acc[3] += xv * wa.w;
    acc[4] += xv * wb2.x; acc[5] += xv * wb2.y;
    acc[6] += xv * wb2.z; acc[7] += xv * wb2.w;
  }
  #pragma unroll
  for (int e = 0; e < 8; ++e) {
    #pragma unroll
    for (int s = 32; s > 0; s >>= 1) acc[e] += __shfl_xor(acc[e], s);
  }
  if (lane == 0) {
    float v[8];
    #pragma unroll
    for (int e = 0; e < 8; ++e) v[e] = acc[e] + bg[e];
    int i1 = -1, i2 = -1;
    float b1v = -1e30f, b2v = -1e30f;
    #pragma unroll
    for (int e = 0; e < 8; ++e) {
      float vv = v[e];
      if (vv > b1v) { b2v = b1v; i2 = i1; b1v = vv; i1 = e; }
      else if (vv > b2v) { b2v = vv; i2 = e; }
    }
    float e2 = __expf(b2v - b1v);
    float inv = 1.f / (1.f + e2);
    float* gr = gdense + (size_t)wave * E_;
    #pragma unroll
    for (int e = 0; e < 8; ++e) gr[e] = 0.f;
    gr[i1] = inv;
    gr[i2] = e2 * inv;
  }
}

// ---------- compaction: per (b,e) ordered token list ----------
__global__ void compact(const float* __restrict__ gdense, int* __restrict__ lists,
                        float* __restrict__ glist, int* __restrict__ cntp,
                        float* __restrict__ G) {
  int be = blockIdx.x;
  int b = be >> 3, e = be & 7;
  __shared__ int warp_off[4];
  __shared__ float wsum[4];
  int tid = threadIdx.x;
  int lane = tid & 63, w = tid >> 6;
  int base = 0;
  float gsum = 0.f;
  for (int c = 0; c < N_; c += 256) {
    int t = b * N_ + c + tid;
    float g = gdense[(size_t)t * E_ + e];
    gsum += g;
    bool sel = g > 0.f;
    unsigned long long m = __ballot(sel);
    int my = __popcll(m & ((1ull << lane) - 1ull));
    int wcnt = __popcll(m);
    if (lane == 0) warp_off[w] = wcnt;
    __syncthreads();
    int off = 0;
    for (int i = 0; i < w; ++i) off += warp_off[i];
    int tot = warp_off[0] + warp_off[1] + warp_off[2] + warp_off[3];
    if (sel) {
      int pos = base + off + my;
      lists[be * N_ + pos] = t;
      glist[be * N_ + pos] = g;
    }
    base += tot;
    __syncthreads();
  }
  if (tid == 0) cntp[be] = base;
  #pragma unroll
  for (int s = 32; s > 0; s >>= 1) gsum += __shfl_xor(gsum, s);
  if (lane == 0) wsum[w] = gsum;
  __syncthreads();
  if (tid == 0) G[be] = wsum[0] + wsum[1] + wsum[2] + wsum[3];
}

// ---------- concat per-expert lists across b; pad to 256-multiple ----------
__global__ void concatE(const int* __restrict__ lists, const float* __restrict__ glist,
                        const int* __restrict__ cntp, int* __restrict__ lists2,
                        float* __restrict__ glist2, int* __restrict__ lenp) {
  int e = blockIdx.x, tid = threadIdx.x;
  __shared__ int off[9];
  if (tid == 0) {
    int s = 0;
    for (int b = 0; b < 8; ++b) { off[b] = s; s += cntp[b * 8 + e]; }
    off[8] = s;
    lenp[e] = (s + 255) & ~255;
  }
  __syncthreads();
  for (int b = 0; b < 8; ++b) {
    int base = off[b], c = cntp[b * 8 + e];
    for (int i = tid; i < c; i += 256) {
      lists2[e * LS_ + base + i] = lists[(b * 8 + e) * N_ + i];
      glist2[e * LS_ + base + i] = glist[(b * 8 + e) * N_ + i];
    }
  }
  __syncthreads();
  int s = off[8], p = (s + 255) & ~255;
  for (int i = s + tid; i < p; i += 256) {
    lists2[e * LS_ + i] = 0;     // token 0 (b=0), gate 0
    glist2[e * LS_ + i] = 0.f;
  }
}

// ---------- out init with bias-2 term: out[b][h] = sum_e G[b,e]*b2[e][h] ----------
__global__ void init_out(const float* __restrict__ G, const float* __restrict__ b2,
                         float* __restrict__ out) {
  int i = blockIdx.x * 256 + threadIdx.x;
  int b = i >> 10, h = i & 1023;
  float acc = 0.f;
  #pragma unroll
  for (int e = 0; e < 8; ++e) acc += G[b * E_ + e] * b2[e * H_ + h];
  out[i] = acc;
}

// ---------- GEMM1: R12 frozen (best measured: 313 us, MfmaUtil 38%) ----------
__launch_bounds__(512, 1)
__global__ void gemm1(const u16* __restrict__ xb, const u16* __restrict__ w1t,
                      const float* __restrict__ b1, const int* __restrict__ lists2,
                      const float* __restrict__ glist2, const int* __restrict__ lenp,
                      float* __restrict__ sbuf) {
  int bid = blockIdx.x;
  int e     = bid & 7;          // XCD id == expert
  int idx   = bid >> 3;
  int ft    = idx & 15;         // 256-wide f tile
  int chunk = idx >> 4;         // 0..17 chunk of concat list
  if (chunk * 256 >= lenp[e]) return;
  int fbase = ft * 256;

  __shared__ u16 sA[2][16384];   // [buf][row256][slot8][8elem], swizzle-stored
  __shared__ u16 sB[2][16384];

  int tid  = threadIdx.x;
  int lane = tid & 63;
  int w    = tid >> 6;
  int wm   = w >> 2;             // rows wm*128
  int wn   = w & 3;              // f cols wn*64
  int fr   = lane & 15;
  int kq   = lane >> 4;          // 0..3
  int r8   = lane >> 3;          // 0..7 staging row-sub
  int sx   = lane & 7;           // staging slot
  int srcSlot = ((sx ^ r8) << 4);  // swizzled byte offset within 128B row segment

  const int* lrow = lists2 + e * LS_ + chunk * 256;
  const char* aP[4];
  const char* bP[4];
  #pragma unroll
  for (int j = 0; j < 4; ++j) {
    int row = j * 64 + w * 8 + r8;
    int tok = lrow[row];
    aP[j] = (const char*)xb + (size_t)tok * 2048 + srcSlot;
    bP[j] = (const char*)w1t + (size_t)(e * F_ + fbase + row) * 2048 + srcSlot;
  }
  int dOff = w * 512;            // u16 units; wave-uniform; +j*4096; HW adds lane*16B

  // read-side indices (short8 units): elem = row*8 + (ks ^ (row&7)); row&7==sx
  int ksl0 = kq ^ sx;            // kh=0
  int ksl1 = (4 + kq) ^ sx;      // kh=1
  int arow = (wm * 128 + fr) * 8;   // + mh*512 + i*128
  int brow = (wn * 64 + fr) * 8;    // + j*128

#define SCHED __builtin_amdgcn_sched_barrier(0)
#define STAGE(t_, bf_) do { \
    _Pragma("unroll") for (int j_ = 0; j_ < 4; ++j_) \
      gll16(aP[j_] + (t_) * 128, &sA[bf_][j_ * 4096 + dOff]); \
    _Pragma("unroll") for (int j_ = 0; j_ < 4; ++j_) \
      gll16(bP[j_] + (t_) * 128, &sB[bf_][j_ * 4096 + dOff]); \
  } while (0)
#define RDA(V_, ks_, mh_) do { _Pragma("unroll") for (int i_ = 0; i_ < 4; ++i_) \
    V_[i_] = Ab[arow + (mh_) * 512 + i_ * 128 + (ks_)]; } while (0)
#define RDB(V_, ks_) do { _Pragma("unroll") for (int j_ = 0; j_ < 4; ++j_) \
    V_[j_] = Bb[brow + j_ * 128 + (ks_)]; } while (0)
#define DOMFMA(mh_, A_, B_) do { _Pragma("unroll") for (int i_ = 0; i_ < 4; ++i_) \
    _Pragma("unroll") for (int j_ = 0; j_ < 4; ++j_) \
      acc[(mh_)*4 + i_][j_] = __builtin_amdgcn_mfma_f32_16x16x32_bf16(A_[i_], B_[j_], acc[(mh_)*4 + i_][j_], 0, 0, 0); \
  } while (0)

  f32x4 acc[8][4];
  #pragma unroll
  for (int i = 0; i < 8; ++i)
    #pragma unroll
    for (int j = 0; j < 4; ++j) acc[i][j] = (f32x4){0.f, 0.f, 0.f, 0.f};

  // prologue: tile 0 in flight
  STAGE(0, 0);

  const int NK = D_ / 64;   // 16
  for (int t = 0; t < NK; ++t) {
    int bf = t & 1;
    const short8* Ab = (const short8*)&sA[bf][0];
    const short8* Bb = (const short8*)&sB[bf][0];

    asm volatile("s_waitcnt vmcnt(0)" ::: "memory");   // own tile-t loads landed
    __builtin_amdgcn_s_barrier();                      // all waves' loads landed
    SCHED;

    short8 a0[4], a1[4], a2[4], a3[4], b0[4], b2[4];
    RDA(a0, ksl0, 0); RDB(b0, ksl0);
    RDA(a1, ksl0, 1);
    if (t + 1 < NK) STAGE(t + 1, bf ^ 1);
    SCHED;
    __builtin_amdgcn_s_setprio(1); DOMFMA(0, a0, b0); __builtin_amdgcn_s_setprio(0);
    RDA(a2, ksl1, 0); RDB(b2, ksl1);
    SCHED;
    __builtin_amdgcn_s_setprio(1); DOMFMA(1, a1, b0); __builtin_amdgcn_s_setprio(0);
    RDA(a3, ksl1, 1);
    SCHED;
    __builtin_amdgcn_s_setprio(1); DOMFMA(0, a2, b2); __builtin_amdgcn_s_setprio(0);
    SCHED;
    __builtin_amdgcn_s_setprio(1); DOMFMA(1, a3, b2); __builtin_amdgcn_s_setprio(0);
    SCHED;
  }
#undef STAGE
#undef RDA
#undef RDB
#undef DOMFMA

  // epilogue: relu(acc + b1) * gate, column-sum split by batch bin
  float b1f[4];
  #pragma unroll
  for (int j = 0; j < 4; ++j)
    b1f[j] = b1[e * F_ + fbase + wn * 64 + j * 16 + fr];
  const float* gRow = glist2 + e * LS_ + chunk * 256;
  int bLo = lrow[0] >> 11;
  float osL[4] = {0.f, 0.f, 0.f, 0.f};
  float osH[4] = {0.f, 0.f, 0.f, 0.f};
  #pragma unroll
  for (int i = 0; i < 8; ++i) {
    int rr = wm * 128 + i * 16 + kq * 4;
    float4 g = *(const float4*)&gRow[rr];
    int4  tv = *(const int4*)&lrow[rr];
    float gl0 = ((tv.x >> 11) == bLo) ? g.x : 0.f;
    float gl1 = ((tv.y >> 11) == bLo) ? g.y : 0.f;
    float gl2 = ((tv.z >> 11) == bLo) ? g.z : 0.f;
    float gl3 = ((tv.w >> 11) == bLo) ? g.w : 0.f;
    float gh0 = g.x - gl0, gh1 = g.y - gl1, gh2 = g.z - gl2, gh3 = g.w - gl3;
    #pragma unroll
    for (int j = 0; j < 4; ++j) {
      float v0 = fmaxf(acc[i][j][0] + b1f[j], 0.f);
      float v1 = fmaxf(acc[i][j][1] + b1f[j], 0.f);
      float v2 = fmaxf(acc[i][j][2] + b1f[j], 0.f);
      float v3 = fmaxf(acc[i][j][3] + b1f[j], 0.f);
      osL[j] += v0 * gl0 + v1 * gl1 + v2 * gl2 + v3 * gl3;
      osH[j] += v0 * gh0 + v1 * gh1 + v2 * gh2 + v3 * gh3;
    }
  }
  #pragma unroll
  for (int j = 0; j < 4; ++j) {
    osL[j] += __shfl_xor(osL[j], 16);
    osL[j] += __shfl_xor(osL[j], 32);
    osH[j] += __shfl_xor(osH[j], 16);
    osH[j] += __shfl_xor(osH[j], 32);
  }
  float* sRedL = (float*)&sA[0][0];
  float* sRedH = sRedL + 256;
  __syncthreads();
  if (wm == 0 && lane < 16) {
    #pragma unroll
    for (int j = 0; j < 4; ++j) {
      sRedL[wn * 64 + j * 16 + lane] = osL[j];
      sRedH[wn * 64 + j * 16 + lane] = osH[j];
    }
  }
  __syncthreads();
  if (wm == 1 && lane < 16) {
    int beL = bLo * 8 + e;
    bool hasHi = bLo < 7;
    int beH = (bLo + 1) * 8 + e;
    #pragma unroll
    for (int j = 0; j < 4; ++j) {
      int fc = wn * 64 + j * 16 + lane;
      atomicAdd(&sbuf[(size_t)beL * F_ + fbase + fc], sRedL[fc] + osL[j]);
      if (hasHi)
        atomicAdd(&sbuf[(size_t)beH * F_ + fbase + fc], sRedH[fc] + osH[j]);
    }
  }
}

// ---------- GEMM2: out[b][h] += sum_f s[b,e,f] * W2[e][f][h] (memory-bound) ----------
__global__ void gemm2(const float* __restrict__ sbuf, const float* __restrict__ W2,
                      float* __restrict__ out) {
  int fc = blockIdx.x;   // 16 chunks of 256 f
  int ht = blockIdx.y;   // 4 tiles of 256 h
  int e  = blockIdx.z;   // 8 experts
  __shared__ float sS[8][256];
  int tid = threadIdx.x;
  #pragma unroll
  for (int b = 0; b < 8; ++b)
    sS[b][tid] = sbuf[((size_t)(b * E_ + e)) * F_ + fc * 256 + tid];
  __syncthreads();
  int h = ht * 256 + tid;
  float acc[8] = {0,0,0,0,0,0,0,0};
  const float* w2p = W2 + (size_t)e * F_ * H_ + (size_t)(fc * 256) * H_ + h;
  for (int f = 0; f < 256; ++f) {
    float wv = w2p[(size_t)f * H_];
    #pragma unroll
    for (int b = 0; b < 8; ++b) acc[b] += sS[b][f] * wv;
  }
  #pragma unroll
  for (int b = 0; b < 8; ++b) atomicAdd(&out[b * H_ + h], acc[b]);
}

extern "C" void kernel_launch(void* const* d_in, const int* in_sizes, int n_in,
                              void* d_out, int out_size, void* d_ws, size_t ws_size,
                              hipStream_t stream) {
  const float* x  = (const float*)d_in[0];
  const float* Wg = (const float*)d_in[1];
  const float* bg = (const float*)d_in[2];
  const float* W1 = (const float*)d_in[3];
  const float* b1 = (const float*)d_in[4];
  const float* W2 = (const float*)d_in[5];
  const float* b2 = (const float*)d_in[6];
  float* out = (float*)d_out;

  char* ws = (char*)d_ws;
  u16*   xb     = (u16*)(ws);
  u16*   w1t    = (u16*)(ws + 33554432);
  float* gdense = (float*)(ws + 100663296);
  int*   lists  = (int*)(ws + 101187584);
  float* glist  = (float*)(ws + 101711872);
  int*   cntp   = (int*)(ws + 102236160);
  float* G      = (float*)(ws + 102236416);
  float* sbuf   = (float*)(ws + 102236672);
  int*   lists2 = (int*)(ws + 103285248);
  float* glist2 = (float*)(ws + 103547392);
  int*   lenp   = (int*)(ws + 103809536);

  hipMemsetAsync(sbuf, 0, (size_t)64 * F_ * sizeof(float), stream);
  cvt_w1<<<dim3(F_/64, D_/64, E_), 256, 0, stream>>>(W1, w1t);
  router<<<T_/4, 256, 0, stream>>>(x, Wg, bg, gdense, xb);
  compact<<<64, 256, 0, stream>>>(gdense, lists, glist, cntp, G);
  concatE<<<8, 256, 0, stream>>>(lists, glist, cntp, lists2, glist2, lenp);
  init_out<<<(B_*H_)/256, 256, 0, stream>>>(G, b2, out);
  gemm1<<<8*16*18, 512, 0, stream>>>(xb, w1t, b1, lists2, glist2, lenp, sbuf);
  gemm2<<<dim3(16, 4, 8), 256, 0, stream>>>(sbuf, W2, out);
}